// Round 2
// baseline (58.854 us; speedup 1.0000x reference)
//
#include <hip/hip_runtime.h>
#include <hip/hip_bf16.h>
#include <math.h>

#ifndef M_PI
#define M_PI 3.14159265358979323846
#endif

namespace mp {

constexpr int NK   = 1024;
constexpr int S    = 256;
constexpr int NREF = 4;
constexpr int BV   = 128;   // B * IT_M
constexpr int BIV  = 2048;  // BV * IT_R

// ---- wave-wide (64-lane) all-reduce sum, identical result on all lanes ----
__device__ inline double wsum(double v) {
#pragma unroll
  for (int m = 32; m >= 1; m >>= 1) v += __shfl_xor(v, m, 64);
  return v;
}

// ---- general 3x3 inverse (adjugate / det), f64 ----
__device__ inline void inv3(const float* __restrict__ K, double Ki[3][3]) {
  double a = K[0], b = K[1], c = K[2];
  double d = K[3], e = K[4], f = K[5];
  double g = K[6], h = K[7], i = K[8];
  double A  =  (e * i - f * h);
  double Bm = -(d * i - f * g);
  double C  =  (d * h - e * g);
  double det = a * A + b * Bm + c * C;
  double inv = 1.0 / det;
  Ki[0][0] = A * inv;  Ki[0][1] = -(b * i - c * h) * inv;  Ki[0][2] =  (b * f - c * e) * inv;
  Ki[1][0] = Bm * inv; Ki[1][1] =  (a * i - c * g) * inv;  Ki[1][2] = -(a * f - c * d) * inv;
  Ki[2][0] = C * inv;  Ki[2][1] = -(a * h - b * g) * inv;  Ki[2][2] =  (a * e - b * d) * inv;
}

// ---- 4x4 symmetric cyclic Jacobi eigensolver (f64). Eigenvalues on diag(A),
//      eigenvectors in columns of V. Converges quadratically; ~6 sweeps. ----
__device__ inline void jacobi4(double A[4][4], double V[4][4]) {
#pragma unroll
  for (int i = 0; i < 4; ++i)
#pragma unroll
    for (int j = 0; j < 4; ++j) V[i][j] = (i == j) ? 1.0 : 0.0;

  for (int sweep = 0; sweep < 15; ++sweep) {
    double off = A[0][1] * A[0][1] + A[0][2] * A[0][2] + A[0][3] * A[0][3] +
                 A[1][2] * A[1][2] + A[1][3] * A[1][3] + A[2][3] * A[2][3];
    double nrm = A[0][0] * A[0][0] + A[1][1] * A[1][1] +
                 A[2][2] * A[2][2] + A[3][3] * A[3][3];
    if (off <= 1e-28 * (nrm + 1e-300)) break;
#pragma unroll
    for (int p = 0; p < 3; ++p) {
#pragma unroll
      for (int q = p + 1; q < 4; ++q) {
        double apq = A[p][q];
        if (fabs(apq) < 1e-300) continue;
        double th = (A[q][q] - A[p][p]) / (2.0 * apq);
        double tt = (th >= 0.0 ? 1.0 : -1.0) / (fabs(th) + sqrt(th * th + 1.0));
        double c = 1.0 / sqrt(tt * tt + 1.0);
        double s = tt * c;
#pragma unroll
        for (int k = 0; k < 4; ++k) {  // A <- A * J (columns p,q)
          double akp = A[k][p], akq = A[k][q];
          A[k][p] = c * akp - s * akq;
          A[k][q] = s * akp + c * akq;
        }
#pragma unroll
        for (int k = 0; k < 4; ++k) {  // A <- J^T * A (rows p,q)
          double apk = A[p][k], aqk = A[q][k];
          A[p][k] = c * apk - s * aqk;
          A[q][k] = s * apk + c * aqk;
        }
#pragma unroll
        for (int k = 0; k < 4; ++k) {  // V <- V * J
          double vkp = V[k][p], vkq = V[k][q];
          V[k][p] = c * vkp - s * vkq;
          V[k][q] = s * vkp + c * vkq;
        }
      }
    }
  }
}

// ---- weighted Procrustes: Y ~= R X + t. Kabsch via Horn quaternion method
//      (max-eigenvector of 4x4 K built from H = sum w (X-cx)(Y-cy)^T).
//      Identical optimum to V diag(1,1,det) U^T. All lanes compute identical
//      R,t (reductions are lane-uniform). ----
__device__ inline void fit(const double X[4][3], const double Y[4][3],
                           const double w[4], double R[3][3], double t[3]) {
  double sw = w[0] + w[1] + w[2] + w[3];
  double sx[3], sy[3];
#pragma unroll
  for (int i = 0; i < 3; ++i) {
    sx[i] = w[0] * X[0][i] + w[1] * X[1][i] + w[2] * X[2][i] + w[3] * X[3][i];
    sy[i] = w[0] * Y[0][i] + w[1] * Y[1][i] + w[2] * Y[2][i] + w[3] * Y[3][i];
  }
  sw = wsum(sw);
  double cx[3], cy[3];
  double swe = sw + 1e-8;
#pragma unroll
  for (int i = 0; i < 3; ++i) {
    sx[i] = wsum(sx[i]);
    sy[i] = wsum(sy[i]);
    cx[i] = sx[i] / swe;
    cy[i] = sy[i] / swe;
  }
  double H[3][3];
#pragma unroll
  for (int i = 0; i < 3; ++i)
#pragma unroll
    for (int j = 0; j < 3; ++j) {
      double h = 0.0;
#pragma unroll
      for (int k = 0; k < 4; ++k) h += w[k] * (X[k][i] - cx[i]) * (Y[k][j] - cy[j]);
      H[i][j] = wsum(h);
    }

  double Kq[4][4];
  Kq[0][0] =  H[0][0] + H[1][1] + H[2][2];
  Kq[1][1] =  H[0][0] - H[1][1] - H[2][2];
  Kq[2][2] = -H[0][0] + H[1][1] - H[2][2];
  Kq[3][3] = -H[0][0] - H[1][1] + H[2][2];
  Kq[0][1] = Kq[1][0] = H[1][2] - H[2][1];
  Kq[0][2] = Kq[2][0] = H[2][0] - H[0][2];
  Kq[0][3] = Kq[3][0] = H[0][1] - H[1][0];
  Kq[1][2] = Kq[2][1] = H[0][1] + H[1][0];
  Kq[1][3] = Kq[3][1] = H[0][2] + H[2][0];
  Kq[2][3] = Kq[3][2] = H[1][2] + H[2][1];

  double V[4][4];
  jacobi4(Kq, V);

  // pick eigenvector of largest eigenvalue (static indexing only)
  double bev = Kq[0][0];
  double qw = V[0][0], qx = V[1][0], qy = V[2][0], qz = V[3][0];
#pragma unroll
  for (int i = 1; i < 4; ++i) {
    bool better = Kq[i][i] > bev;
    bev = better ? Kq[i][i] : bev;
    qw = better ? V[0][i] : qw;
    qx = better ? V[1][i] : qx;
    qy = better ? V[2][i] : qy;
    qz = better ? V[3][i] : qz;
  }
  double qn = 1.0 / sqrt(qw * qw + qx * qx + qy * qy + qz * qz);
  qw *= qn; qx *= qn; qy *= qn; qz *= qn;

  R[0][0] = 1.0 - 2.0 * (qy * qy + qz * qz);
  R[0][1] = 2.0 * (qx * qy - qw * qz);
  R[0][2] = 2.0 * (qx * qz + qw * qy);
  R[1][0] = 2.0 * (qx * qy + qw * qz);
  R[1][1] = 1.0 - 2.0 * (qx * qx + qz * qz);
  R[1][2] = 2.0 * (qy * qz - qw * qx);
  R[2][0] = 2.0 * (qx * qz - qw * qy);
  R[2][1] = 2.0 * (qy * qz + qw * qx);
  R[2][2] = 1.0 - 2.0 * (qx * qx + qy * qy);
#pragma unroll
  for (int i = 0; i < 3; ++i)
    t[i] = cy[i] - (R[i][0] * cx[0] + R[i][1] * cx[1] + R[i][2] * cx[2]);
}

// ---- one wave (64 lanes) per RANSAC candidate m in [0,2048); 4 points/lane ----
__global__ __launch_bounds__(64, 1) void pose_fit_kernel(
    const float* __restrict__ kps0, const float* __restrict__ kps1,
    const float* __restrict__ depth0, const float* __restrict__ depth1,
    const float* __restrict__ T01,
    const float* __restrict__ K0, const float* __restrict__ K1,
    const int* __restrict__ sidx, const int* __restrict__ sransac,
    double* __restrict__ oscore, double* __restrict__ olr,
    double* __restrict__ olt) {
  const int m = blockIdx.x;      // candidate (0..2047)
  const int v = m >> 4;          // sample row (0..127), IT_R = 16
  const int b = v >> 4;          // batch (0..7), IT_M = 16
  const int lane = threadIdx.x;  // 0..63

  double Ki0[3][3], Ki1[3][3];
  inv3(K0 + b * 9, Ki0);
  inv3(K1 + b * 9, Ki1);

  // gather + backproject 4 points per lane (f64)
  double X[4][3], Y[4][3];
#pragma unroll
  for (int k = 0; k < 4; ++k) {
    int s = lane + 64 * k;
    int idx = sidx[v * S + s];
    int i0 = idx >> 10;       // idx / NK
    int i1 = idx & (NK - 1);  // idx % NK
    double u0 = (double)kps0[b * 2 * NK + i0];
    double w0 = (double)kps0[b * 2 * NK + NK + i0];
    double d0 = (double)depth0[b * NK + i0];
    double u1 = (double)kps1[b * 2 * NK + i1];
    double w1 = (double)kps1[b * 2 * NK + NK + i1];
    double d1 = (double)depth1[b * NK + i1];
#pragma unroll
    for (int i = 0; i < 3; ++i) {
      X[k][i] = d0 * (Ki0[i][0] * u0 + Ki0[i][1] * w0 + Ki0[i][2]);
      Y[k][i] = d1 * (Ki1[i][0] * u1 + Ki1[i][1] * w1 + Ki1[i][2]);
    }
  }

  // initial inlier mask from the 5 ransac seed indices
  int r5[5];
#pragma unroll
  for (int c = 0; c < 5; ++c) r5[c] = sransac[m * 5 + c];
  double w[4], wfin[4];
#pragma unroll
  for (int k = 0; k < 4; ++k) {
    int s = lane + 64 * k;
    double val = 0.0;
#pragma unroll
    for (int c = 0; c < 5; ++c) val = (r5[c] == s) ? 1.0 : val;
    w[k] = val;
    wfin[k] = val;
  }

  double pre = 5.0;  // NC
  double R[3][3], t[3];
  for (int it = 0; it < NREF; ++it) {
    fit(X, Y, w, R, t);
    double ref[4];
    double rs = 0.0;
#pragma unroll
    for (int k = 0; k < 4; ++k) {
      double e0 = Y[k][0] - (R[0][0] * X[k][0] + R[0][1] * X[k][1] + R[0][2] * X[k][2] + t[0]);
      double e1 = Y[k][1] - (R[1][0] * X[k][0] + R[1][1] * X[k][1] + R[1][2] * X[k][2] + t[1]);
      double e2 = Y[k][2] - (R[2][0] * X[k][0] + R[2][1] * X[k][1] + R[2][2] * X[k][2] + t[2]);
      double r2 = sqrt(e0 * e0 + e1 * e1 + e2 * e2);
      ref[k] = (r2 < 0.15) ? 1.0 : 0.0;
      rs += ref[k];
    }
    double refsum = wsum(rs);  // lane-uniform
    if (refsum > pre) {
      pre = refsum;
#pragma unroll
      for (int k = 0; k < 4; ++k) {
        wfin[k] = w[k];  // reference: inl_final <- inl (the weights that were FIT)
        w[k] = ref[k];   //            inl <- ref
      }
    } else {
      // fixed point: identical weights -> identical fit -> identical ref ->
      // improved stays false for all remaining iterations. Exact early-out.
      break;
    }
  }

  // final fit with inl_final + smooth score
  fit(X, Y, wfin, R, t);
  double sc = 0.0;
#pragma unroll
  for (int k = 0; k < 4; ++k) {
    double e0 = Y[k][0] - (R[0][0] * X[k][0] + R[0][1] * X[k][1] + R[0][2] * X[k][2] + t[0]);
    double e1 = Y[k][1] - (R[1][0] * X[k][0] + R[1][1] * X[k][1] + R[1][2] * X[k][2] + t[1]);
    double e2 = Y[k][2] - (R[2][0] * X[k][0] + R[2][1] * X[k][1] + R[2][2] * X[k][2] + t[2]);
    double r2 = sqrt(e0 * e0 + e1 * e1 + e2 * e2);
    double xar = 5.0 * (1.0 - r2 / 0.15);  // BETA * (1 - r/TH)
    sc += 1.0 / (1.0 + exp(-xar));
  }
  double score = wsum(sc);

  // pose errors vs ground truth T_0to1[b]
  const float* Tb = T01 + b * 16;
  double tr = 0.0;
#pragma unroll
  for (int i = 0; i < 3; ++i)
#pragma unroll
    for (int j = 0; j < 3; ++j) tr += R[i][j] * (double)Tb[i * 4 + j];
  double xcl = 0.5 * (tr - 1.0);
  const double lo = -1.0 + 1e-6, hi = 1.0 - 1e-6;
  xcl = xcl < lo ? lo : (xcl > hi ? hi : xcl);
  double rot_err = acos(xcl) * (180.0 / M_PI);
  double te0 = t[0] - (double)Tb[3];
  double te1 = t[1] - (double)Tb[7];
  double te2 = t[2] - (double)Tb[11];
  double terr = sqrt(te0 * te0 + te1 * te1 + te2 * te2);

  if (lane == 0) {
    oscore[m] = score;
    olr[m] = 45.0 * tanh(rot_err / 45.0);  // MAX_ROT
    olt[m] = tanh(terr);                   // MAX_TRANS = 1
  }
}

// ---- softmax(score/TEMP) over IT_R=16, weighted losses, mean over IT_M=16 ----
// Output is FLOAT32 (reference returns f32), flat (2, B, 1) = [rot x8, trans x8].
__global__ __launch_bounds__(128) void pose_reduce_kernel(
    const double* __restrict__ oscore, const double* __restrict__ olr,
    const double* __restrict__ olt, float* __restrict__ out) {
  __shared__ double slr[BV], slt[BV];
  int k = threadIdx.x;  // bv index 0..127
  double sc[16];
  double mx = -1e300;
#pragma unroll
  for (int r = 0; r < 16; ++r) {
    sc[r] = oscore[k * 16 + r];
    mx = fmax(mx, sc[r]);
  }
  double den = 0.0, wl = 0.0, wt = 0.0;
#pragma unroll
  for (int r = 0; r < 16; ++r) {
    double e = exp((sc[r] - mx) / 10.0);  // TEMP
    den += e;
    wl += e * olr[k * 16 + r];
    wt += e * olt[k * 16 + r];
  }
  slr[k] = wl / den;
  slt[k] = wt / den;
  __syncthreads();
  if (k < 8) {
    double a = 0.0, c = 0.0;
#pragma unroll
    for (int i = 0; i < 16; ++i) {
      a += slr[k * 16 + i];
      c += slt[k * 16 + i];
    }
    out[k]     = (float)(a / 16.0);  // losses_rot,   (2,B,1) flat
    out[8 + k] = (float)(c / 16.0);  // losses_trans
  }
}

}  // namespace mp

extern "C" void kernel_launch(void* const* d_in, const int* in_sizes, int n_in,
                              void* d_out, int out_size, void* d_ws, size_t ws_size,
                              hipStream_t stream) {
  // input order per setup_inputs(): 0 matches (unused), 1 kps0, 2 kps1,
  // 3 depth0, 4 depth1, 5 T_0to1, 6 K_color0, 7 K_color1, 8/9 Kori (unused),
  // 10 sampled_idx, 11 sampled_idx_ransac
  const float* kps0   = (const float*)d_in[1];
  const float* kps1   = (const float*)d_in[2];
  const float* depth0 = (const float*)d_in[3];
  const float* depth1 = (const float*)d_in[4];
  const float* T01    = (const float*)d_in[5];
  const float* K0     = (const float*)d_in[6];
  const float* K1     = (const float*)d_in[7];
  const int* sidx     = (const int*)d_in[10];
  const int* srans    = (const int*)d_in[11];

  double* ws     = (double*)d_ws;       // 3 * 2048 * 8B = 48 KB scratch
  double* oscore = ws;
  double* olr    = ws + mp::BIV;
  double* olt    = ws + 2 * mp::BIV;

  mp::pose_fit_kernel<<<mp::BIV, 64, 0, stream>>>(
      kps0, kps1, depth0, depth1, T01, K0, K1, sidx, srans, oscore, olr, olt);
  mp::pose_reduce_kernel<<<1, 128, 0, stream>>>(
      oscore, olr, olt, (float*)d_out);
}

// Round 3
// 32.437 us; speedup vs baseline: 1.8144x; 1.8144x over previous
//
#include <hip/hip_runtime.h>
#include <hip/hip_bf16.h>
#include <math.h>

#ifndef M_PI
#define M_PI 3.14159265358979323846
#endif

namespace mp {

constexpr int NK   = 1024;
constexpr int S    = 256;
constexpr int NREF = 4;
constexpr int BV   = 128;   // B * IT_M
constexpr int BIV  = 2048;  // BV * IT_R

// ---- wave-wide (64-lane) all-reduce sum, identical result on all lanes ----
__device__ inline double wsum(double v) {
#pragma unroll
  for (int m = 32; m >= 1; m >>= 1) v += __shfl_xor(v, m, 64);
  return v;
}
__device__ inline float wsumf(float v) {
#pragma unroll
  for (int m = 32; m >= 1; m >>= 1) v += __shfl_xor(v, m, 64);
  return v;
}

// ---- general 3x3 inverse (adjugate / det), f64 ----
__device__ inline void inv3(const float* __restrict__ K, double Ki[3][3]) {
  double a = K[0], b = K[1], c = K[2];
  double d = K[3], e = K[4], f = K[5];
  double g = K[6], h = K[7], i = K[8];
  double A  =  (e * i - f * h);
  double Bm = -(d * i - f * g);
  double C  =  (d * h - e * g);
  double det = a * A + b * Bm + c * C;
  double inv = 1.0 / det;
  Ki[0][0] = A * inv;  Ki[0][1] = -(b * i - c * h) * inv;  Ki[0][2] =  (b * f - c * e) * inv;
  Ki[1][0] = Bm * inv; Ki[1][1] =  (a * i - c * g) * inv;  Ki[1][2] = -(a * f - c * d) * inv;
  Ki[2][0] = C * inv;  Ki[2][1] = -(a * h - b * g) * inv;  Ki[2][2] =  (a * e - b * d) * inv;
}

// ---- 4x4 symmetric cyclic Jacobi, f64, symmetric-aware updates.
//      Eigenvalues on diag(A), eigenvectors in columns of V. ----
__device__ inline void jacobi4(double A[4][4], double V[4][4]) {
#pragma unroll
  for (int i = 0; i < 4; ++i)
#pragma unroll
    for (int j = 0; j < 4; ++j) V[i][j] = (i == j) ? 1.0 : 0.0;

  for (int sweep = 0; sweep < 12; ++sweep) {
    double off = A[0][1] * A[0][1] + A[0][2] * A[0][2] + A[0][3] * A[0][3] +
                 A[1][2] * A[1][2] + A[1][3] * A[1][3] + A[2][3] * A[2][3];
    double nrm = A[0][0] * A[0][0] + A[1][1] * A[1][1] +
                 A[2][2] * A[2][2] + A[3][3] * A[3][3];
    if (off <= 1e-28 * (nrm + 1e-300)) break;
#pragma unroll
    for (int p = 0; p < 3; ++p) {
#pragma unroll
      for (int q = p + 1; q < 4; ++q) {
        double apq = A[p][q];
        if (apq != 0.0) {  // lane-uniform branch (A identical across lanes)
          double th = (A[q][q] - A[p][p]) / (2.0 * apq);
          double tt = (th >= 0.0 ? 1.0 : -1.0) / (fabs(th) + sqrt(th * th + 1.0));
          double c = 1.0 / sqrt(tt * tt + 1.0);
          double s = tt * c;
          double tapq = tt * apq;
          A[p][p] -= tapq;
          A[q][q] += tapq;
          A[p][q] = 0.0;
          A[q][p] = 0.0;
#pragma unroll
          for (int k = 0; k < 4; ++k) {
            if (k != p && k != q) {  // compile-time condition
              double akp = A[k][p], akq = A[k][q];
              double nkp = c * akp - s * akq;
              double nkq = s * akp + c * akq;
              A[k][p] = nkp; A[p][k] = nkp;
              A[k][q] = nkq; A[q][k] = nkq;
            }
          }
#pragma unroll
          for (int k = 0; k < 4; ++k) {
            double vkp = V[k][p], vkq = V[k][q];
            V[k][p] = c * vkp - s * vkq;
            V[k][q] = s * vkp + c * vkq;
          }
        }
      }
    }
  }
}

// ---- weighted Procrustes: Y ~= R X + t. Horn quaternion method (equivalent
//      optimum to Kabsch V diag(1,1,det) U^T). One-pass moment reduction:
//      H = S - cx*sy^T - sx*cy^T + sw*cx*cy^T  (matches reference's
//      sw+1e-8 epsilon semantics exactly in the algebra). ----
__device__ inline void fit(const double X[4][3], const double Y[4][3],
                           const double w[4], double R[3][3], double t[3]) {
  // acc: [0]=sw, [1..3]=sx, [4..6]=sy, [7+3i+j]=Sxy[i][j]
  double acc[16];
  acc[0] = w[0] + w[1] + w[2] + w[3];
#pragma unroll
  for (int i = 0; i < 3; ++i) {
    acc[1 + i] = w[0] * X[0][i] + w[1] * X[1][i] + w[2] * X[2][i] + w[3] * X[3][i];
    acc[4 + i] = w[0] * Y[0][i] + w[1] * Y[1][i] + w[2] * Y[2][i] + w[3] * Y[3][i];
  }
#pragma unroll
  for (int i = 0; i < 3; ++i)
#pragma unroll
    for (int j = 0; j < 3; ++j) {
      double v = 0.0;
#pragma unroll
      for (int k = 0; k < 4; ++k) v += w[k] * X[k][i] * Y[k][j];
      acc[7 + 3 * i + j] = v;
    }
  // single interleaved butterfly: 16 independent chains, 6 levels
#pragma unroll
  for (int m = 32; m >= 1; m >>= 1)
#pragma unroll
    for (int r = 0; r < 16; ++r) acc[r] += __shfl_xor(acc[r], m, 64);

  double sw = acc[0];
  double swe = sw + 1e-8;
  double cx[3], cy[3];
#pragma unroll
  for (int i = 0; i < 3; ++i) { cx[i] = acc[1 + i] / swe; cy[i] = acc[4 + i] / swe; }
  double H[3][3];
#pragma unroll
  for (int i = 0; i < 3; ++i)
#pragma unroll
    for (int j = 0; j < 3; ++j)
      H[i][j] = acc[7 + 3 * i + j] - cx[i] * acc[4 + j] - acc[1 + i] * cy[j] +
                sw * cx[i] * cy[j];

  double Kq[4][4];
  Kq[0][0] =  H[0][0] + H[1][1] + H[2][2];
  Kq[1][1] =  H[0][0] - H[1][1] - H[2][2];
  Kq[2][2] = -H[0][0] + H[1][1] - H[2][2];
  Kq[3][3] = -H[0][0] - H[1][1] + H[2][2];
  Kq[0][1] = Kq[1][0] = H[1][2] - H[2][1];
  Kq[0][2] = Kq[2][0] = H[2][0] - H[0][2];
  Kq[0][3] = Kq[3][0] = H[0][1] - H[1][0];
  Kq[1][2] = Kq[2][1] = H[0][1] + H[1][0];
  Kq[1][3] = Kq[3][1] = H[0][2] + H[2][0];
  Kq[2][3] = Kq[3][2] = H[1][2] + H[2][1];

  double V[4][4];
  jacobi4(Kq, V);

  // eigenvector of largest eigenvalue (static indexing)
  double bev = Kq[0][0];
  double qw = V[0][0], qx = V[1][0], qy = V[2][0], qz = V[3][0];
#pragma unroll
  for (int i = 1; i < 4; ++i) {
    bool better = Kq[i][i] > bev;
    bev = better ? Kq[i][i] : bev;
    qw = better ? V[0][i] : qw;
    qx = better ? V[1][i] : qx;
    qy = better ? V[2][i] : qy;
    qz = better ? V[3][i] : qz;
  }
  double qn = 1.0 / sqrt(qw * qw + qx * qx + qy * qy + qz * qz);
  qw *= qn; qx *= qn; qy *= qn; qz *= qn;

  R[0][0] = 1.0 - 2.0 * (qy * qy + qz * qz);
  R[0][1] = 2.0 * (qx * qy - qw * qz);
  R[0][2] = 2.0 * (qx * qz + qw * qy);
  R[1][0] = 2.0 * (qx * qy + qw * qz);
  R[1][1] = 1.0 - 2.0 * (qx * qx + qz * qz);
  R[1][2] = 2.0 * (qy * qz - qw * qx);
  R[2][0] = 2.0 * (qx * qz - qw * qy);
  R[2][1] = 2.0 * (qy * qz + qw * qx);
  R[2][2] = 1.0 - 2.0 * (qx * qx + qy * qy);
#pragma unroll
  for (int i = 0; i < 3; ++i)
    t[i] = cy[i] - (R[i][0] * cx[0] + R[i][1] * cx[1] + R[i][2] * cx[2]);
}

// ---- one wave (64 lanes) per RANSAC candidate m in [0,2048); 4 points/lane.
// Key exactness: the reference's final procrustes(Xv,Yv,inl_final) always
// re-fits weights that were already fit inside the loop (inl_final is the
// inl of the last improving iteration, or inl0 if none improved, which is
// iteration 0's weights). So we save R,t (and residuals) at it==0 and at
// each improving iteration -> the final fit is free and bit-identical. ----
__global__ __launch_bounds__(64) void pose_fit_kernel(
    const float* __restrict__ kps0, const float* __restrict__ kps1,
    const float* __restrict__ depth0, const float* __restrict__ depth1,
    const float* __restrict__ T01,
    const float* __restrict__ K0, const float* __restrict__ K1,
    const int* __restrict__ sidx, const int* __restrict__ sransac,
    double* __restrict__ oscore, double* __restrict__ olr,
    double* __restrict__ olt) {
  const int m = blockIdx.x;      // candidate (0..2047)
  const int v = m >> 4;          // sample row (0..127), IT_R = 16
  const int b = v >> 4;          // batch (0..7), IT_M = 16
  const int lane = threadIdx.x;  // 0..63

  double Ki0[3][3], Ki1[3][3];
  inv3(K0 + b * 9, Ki0);
  inv3(K1 + b * 9, Ki1);

  // gather + backproject 4 points per lane (f64)
  double X[4][3], Y[4][3];
#pragma unroll
  for (int k = 0; k < 4; ++k) {
    int s = lane + 64 * k;
    int idx = sidx[v * S + s];
    int i0 = idx >> 10;       // idx / NK
    int i1 = idx & (NK - 1);  // idx % NK
    double u0 = (double)kps0[b * 2 * NK + i0];
    double w0 = (double)kps0[b * 2 * NK + NK + i0];
    double d0 = (double)depth0[b * NK + i0];
    double u1 = (double)kps1[b * 2 * NK + i1];
    double w1 = (double)kps1[b * 2 * NK + NK + i1];
    double d1 = (double)depth1[b * NK + i1];
#pragma unroll
    for (int i = 0; i < 3; ++i) {
      X[k][i] = d0 * (Ki0[i][0] * u0 + Ki0[i][1] * w0 + Ki0[i][2]);
      Y[k][i] = d1 * (Ki1[i][0] * u1 + Ki1[i][1] * w1 + Ki1[i][2]);
    }
  }

  // initial inlier mask from the 5 ransac seed indices
  int r5[5];
#pragma unroll
  for (int c = 0; c < 5; ++c) r5[c] = sransac[m * 5 + c];
  double w[4];
#pragma unroll
  for (int k = 0; k < 4; ++k) {
    int s = lane + 64 * k;
    double val = 0.0;
#pragma unroll
    for (int c = 0; c < 5; ++c) val = (r5[c] == s) ? 1.0 : val;
    w[k] = val;
  }

  double pre = 5.0;  // NC
  double R[3][3], t[3];
  double Rf[3][3], tf[3];  // fit corresponding to inl_final
  double r2f[4];           // residuals under Rf,tf (for the score)
  for (int it = 0; it < NREF; ++it) {
    fit(X, Y, w, R, t);
    double ref[4], r2[4];
    double rs = 0.0;
#pragma unroll
    for (int k = 0; k < 4; ++k) {
      double e0 = Y[k][0] - (R[0][0] * X[k][0] + R[0][1] * X[k][1] + R[0][2] * X[k][2] + t[0]);
      double e1 = Y[k][1] - (R[1][0] * X[k][0] + R[1][1] * X[k][1] + R[1][2] * X[k][2] + t[1]);
      double e2 = Y[k][2] - (R[2][0] * X[k][0] + R[2][1] * X[k][1] + R[2][2] * X[k][2] + t[2]);
      r2[k] = sqrt(e0 * e0 + e1 * e1 + e2 * e2);
      ref[k] = (r2[k] < 0.15) ? 1.0 : 0.0;
      rs += ref[k];
    }
    double refsum = wsum(rs);          // lane-uniform
    bool improved = refsum > pre;
    if (it == 0 || improved) {         // this fit is (currently) the final one
#pragma unroll
      for (int i = 0; i < 3; ++i) {
#pragma unroll
        for (int j = 0; j < 3; ++j) Rf[i][j] = R[i][j];
        tf[i] = t[i];
      }
#pragma unroll
      for (int k = 0; k < 4; ++k) r2f[k] = r2[k];
    }
    if (improved) {
      pre = refsum;
#pragma unroll
      for (int k = 0; k < 4; ++k) w[k] = ref[k];
    } else {
      // fixed point: identical weights -> identical fit -> improved stays
      // false for all remaining iterations. Exact early-out.
      break;
    }
  }

  // smooth score from saved residuals (f32 tail: smooth path, no thresholds)
  float sc = 0.0f;
#pragma unroll
  for (int k = 0; k < 4; ++k) {
    float xar = 5.0f * (1.0f - (float)r2f[k] * (1.0f / 0.15f));  // BETA*(1-r/TH)
    sc += 1.0f / (1.0f + __expf(-xar));
  }
  float score = wsumf(sc);

  // pose errors vs ground truth T_0to1[b] (smooth path -> f32 transcendentals)
  const float* Tb = T01 + b * 16;
  double tr = 0.0;
#pragma unroll
  for (int i = 0; i < 3; ++i)
#pragma unroll
    for (int j = 0; j < 3; ++j) tr += Rf[i][j] * (double)Tb[i * 4 + j];
  double xcl = 0.5 * (tr - 1.0);
  const double lo = -1.0 + 1e-6, hi = 1.0 - 1e-6;
  xcl = xcl < lo ? lo : (xcl > hi ? hi : xcl);
  float rot_err = acosf((float)xcl) * (float)(180.0 / M_PI);
  double te0 = tf[0] - (double)Tb[3];
  double te1 = tf[1] - (double)Tb[7];
  double te2 = tf[2] - (double)Tb[11];
  float terr = sqrtf((float)(te0 * te0 + te1 * te1 + te2 * te2));
  float lr = 45.0f * tanhf(rot_err * (1.0f / 45.0f));  // MAX_ROT
  float lt = tanhf(terr);                              // MAX_TRANS = 1

  if (lane == 0) {
    oscore[m] = (double)score;
    olr[m] = (double)lr;
    olt[m] = (double)lt;
  }
}

// ---- softmax(score/TEMP) over IT_R=16, weighted losses, mean over IT_M=16 ----
// Output is FLOAT32, flat (2, B, 1) = [rot x8, trans x8].
__global__ __launch_bounds__(128) void pose_reduce_kernel(
    const double* __restrict__ oscore, const double* __restrict__ olr,
    const double* __restrict__ olt, float* __restrict__ out) {
  __shared__ double slr[BV], slt[BV];
  int k = threadIdx.x;  // bv index 0..127
  double sc[16];
  double mx = -1e300;
#pragma unroll
  for (int r = 0; r < 16; ++r) {
    sc[r] = oscore[k * 16 + r];
    mx = fmax(mx, sc[r]);
  }
  double den = 0.0, wl = 0.0, wt = 0.0;
#pragma unroll
  for (int r = 0; r < 16; ++r) {
    double e = (double)__expf((float)((sc[r] - mx) * 0.1));  // /TEMP
    den += e;
    wl += e * olr[k * 16 + r];
    wt += e * olt[k * 16 + r];
  }
  slr[k] = wl / den;
  slt[k] = wt / den;
  __syncthreads();
  if (k < 8) {
    double a = 0.0, c = 0.0;
#pragma unroll
    for (int i = 0; i < 16; ++i) {
      a += slr[k * 16 + i];
      c += slt[k * 16 + i];
    }
    out[k]     = (float)(a / 16.0);  // losses_rot,   (2,B,1) flat
    out[8 + k] = (float)(c / 16.0);  // losses_trans
  }
}

}  // namespace mp

extern "C" void kernel_launch(void* const* d_in, const int* in_sizes, int n_in,
                              void* d_out, int out_size, void* d_ws, size_t ws_size,
                              hipStream_t stream) {
  // input order per setup_inputs(): 0 matches (unused), 1 kps0, 2 kps1,
  // 3 depth0, 4 depth1, 5 T_0to1, 6 K_color0, 7 K_color1, 8/9 Kori (unused),
  // 10 sampled_idx, 11 sampled_idx_ransac
  const float* kps0   = (const float*)d_in[1];
  const float* kps1   = (const float*)d_in[2];
  const float* depth0 = (const float*)d_in[3];
  const float* depth1 = (const float*)d_in[4];
  const float* T01    = (const float*)d_in[5];
  const float* K0     = (const float*)d_in[6];
  const float* K1     = (const float*)d_in[7];
  const int* sidx     = (const int*)d_in[10];
  const int* srans    = (const int*)d_in[11];

  double* ws     = (double*)d_ws;  // 3 * 2048 * 8B = 48 KB scratch
  double* oscore = ws;
  double* olr    = ws + mp::BIV;
  double* olt    = ws + 2 * mp::BIV;

  mp::pose_fit_kernel<<<mp::BIV, 64, 0, stream>>>(
      kps0, kps1, depth0, depth1, T01, K0, K1, sidx, srans, oscore, olr, olt);
  mp::pose_reduce_kernel<<<1, 128, 0, stream>>>(
      oscore, olr, olt, (float*)d_out);
}

// Round 4
// 25.277 us; speedup vs baseline: 2.3284x; 1.2833x over previous
//
#include <hip/hip_runtime.h>
#include <hip/hip_bf16.h>
#include <math.h>

#ifndef M_PI
#define M_PI 3.14159265358979323846
#endif

namespace mp {

constexpr int NK   = 1024;
constexpr int S    = 256;
constexpr int NREF = 4;
constexpr int BV   = 128;   // B * IT_M
constexpr int BIV  = 2048;  // BV * IT_R

// ---- wave-wide (64-lane) all-reduce sum, identical result on all lanes ----
__device__ inline double wsum(double v) {
#pragma unroll
  for (int m = 32; m >= 1; m >>= 1) v += __shfl_xor(v, m, 64);
  return v;
}
__device__ inline float wsumf(float v) {
#pragma unroll
  for (int m = 32; m >= 1; m >>= 1) v += __shfl_xor(v, m, 64);
  return v;
}

// ---- general 3x3 inverse (adjugate / det), f64 ----
__device__ inline void inv3(const float* __restrict__ K, double Ki[3][3]) {
  double a = K[0], b = K[1], c = K[2];
  double d = K[3], e = K[4], f = K[5];
  double g = K[6], h = K[7], i = K[8];
  double A  =  (e * i - f * h);
  double Bm = -(d * i - f * g);
  double C  =  (d * h - e * g);
  double det = a * A + b * Bm + c * C;
  double inv = 1.0 / det;
  Ki[0][0] = A * inv;  Ki[0][1] = -(b * i - c * h) * inv;  Ki[0][2] =  (b * f - c * e) * inv;
  Ki[1][0] = Bm * inv; Ki[1][1] =  (a * i - c * g) * inv;  Ki[1][2] = -(a * f - c * d) * inv;
  Ki[2][0] = C * inv;  Ki[2][1] = -(a * h - b * g) * inv;  Ki[2][2] =  (a * e - b * d) * inv;
}

// ---- Jacobi rotation params, div/sqrt-free (2x f64 rsqrt, branchless skip).
//      Zeroes apq with |phi| <= pi/4. cos2phi = sigma*b*rsqrt(a^2+b^2) >= 0,
//      c = (1+c2)*u, s = s2*u with u = rsqrt(2+2*c2)  (cancellation-free:
//      (1-c2)/2 == s2^2/(2*(1+c2))). ----
__device__ inline void rot2(double app, double aqq, double apq,
                            double& c, double& s) {
  double a = 2.0 * apq, b = aqq - app;
  bool sk = (apq * apq) <= 1e-30 * (app * app + aqq * aqq + 1e-300);
  double w = rsqrt(a * a + b * b + 1e-300);
  double sg = (b >= 0.0) ? 1.0 : -1.0;
  double c2 = sg * b * w;          // >= 0
  double s2 = sg * a * w;
  double u = rsqrt(2.0 + 2.0 * c2);
  double cc = (1.0 + c2) * u;
  double ss = s2 * u;
  c = sk ? 1.0 : cc;
  s = sk ? 0.0 : ss;
}

// ---- one Brent-Luk stage: two disjoint rotations (P,Q) and (R_,S_),
//      data-independent c,s -> 2x ILP on the serial chain. A <- J^T A J,
//      V <- V J, J = [[c,s],[-s,c]] on each index pair. ----
template <int P, int Q, int R_, int S_>
__device__ inline void jstage(double A[4][4], double V[4][4]) {
  double app = A[P][P], aqq = A[Q][Q], apq = A[P][Q];
  double arr = A[R_][R_], ass = A[S_][S_], ars = A[R_][S_];
  double c1, s1, c2, s2;
  rot2(app, aqq, apq, c1, s1);
  rot2(arr, ass, ars, c2, s2);

  // diagonal 2x2 blocks (full c^2/s^2 form, no tan needed)
  double cs1 = c1 * s1, c1q = c1 * c1, s1q = s1 * s1;
  A[P][P] = c1q * app - 2.0 * cs1 * apq + s1q * aqq;
  A[Q][Q] = s1q * app + 2.0 * cs1 * apq + c1q * aqq;
  // rotation chosen to zero apq; when skipped apq is already ~1e-15*scale
  A[P][Q] = 0.0; A[Q][P] = 0.0;
  double cs2 = c2 * s2, c2q = c2 * c2, s2q = s2 * s2;
  A[R_][R_] = c2q * arr - 2.0 * cs2 * ars + s2q * ass;
  A[S_][S_] = s2q * arr + 2.0 * cs2 * ars + c2q * ass;
  A[R_][S_] = 0.0; A[S_][R_] = 0.0;

  // off-block rows{P,Q} x cols{R_,S_}: row-rotate by (c1,s1), col by (c2,s2)
  double m11 = A[P][R_], m12 = A[P][S_], m21 = A[Q][R_], m22 = A[Q][S_];
  double n11 = c1 * m11 - s1 * m21, n12 = c1 * m12 - s1 * m22;
  double n21 = s1 * m11 + c1 * m21, n22 = s1 * m12 + c1 * m22;
  double p11 = c2 * n11 - s2 * n12, p12 = s2 * n11 + c2 * n12;
  double p21 = c2 * n21 - s2 * n22, p22 = s2 * n21 + c2 * n22;
  A[P][R_] = p11; A[R_][P] = p11;
  A[P][S_] = p12; A[S_][P] = p12;
  A[Q][R_] = p21; A[R_][Q] = p21;
  A[Q][S_] = p22; A[S_][Q] = p22;

  // eigenvector accumulation: V <- V J1 J2 (disjoint column pairs)
#pragma unroll
  for (int k = 0; k < 4; ++k) {
    double vp = V[k][P], vq = V[k][Q];
    V[k][P] = c1 * vp - s1 * vq;
    V[k][Q] = s1 * vp + c1 * vq;
    double vr = V[k][R_], vs = V[k][S_];
    V[k][R_] = c2 * vr - s2 * vs;
    V[k][S_] = s2 * vr + c2 * vs;
  }
}

// ---- 4x4 symmetric Jacobi, parallel (Brent-Luk) ordering, fixed 5 sweeps.
//      Eigenvalues on diag(A), eigenvectors in columns of V. ----
__device__ inline void jacobi4(double A[4][4], double V[4][4]) {
#pragma unroll
  for (int i = 0; i < 4; ++i)
#pragma unroll
    for (int j = 0; j < 4; ++j) V[i][j] = (i == j) ? 1.0 : 0.0;
#pragma unroll
  for (int sweep = 0; sweep < 5; ++sweep) {
    jstage<0, 1, 2, 3>(A, V);
    jstage<0, 2, 1, 3>(A, V);
    jstage<0, 3, 1, 2>(A, V);
  }
}

// ---- weighted Procrustes: Y ~= R X + t. Horn quaternion method (equivalent
//      optimum to Kabsch V diag(1,1,det) U^T). One-pass moment reduction:
//      H = S - cx*sy^T - sx*cy^T + sw*cx*cy^T  (reproduces reference's
//      sw+1e-8 epsilon semantics). ----
__device__ inline void fit(const double X[4][3], const double Y[4][3],
                           const double w[4], double R[3][3], double t[3]) {
  // acc: [0]=sw, [1..3]=sx, [4..6]=sy, [7+3i+j]=Sxy[i][j]
  double acc[16];
  acc[0] = w[0] + w[1] + w[2] + w[3];
#pragma unroll
  for (int i = 0; i < 3; ++i) {
    acc[1 + i] = w[0] * X[0][i] + w[1] * X[1][i] + w[2] * X[2][i] + w[3] * X[3][i];
    acc[4 + i] = w[0] * Y[0][i] + w[1] * Y[1][i] + w[2] * Y[2][i] + w[3] * Y[3][i];
  }
#pragma unroll
  for (int i = 0; i < 3; ++i)
#pragma unroll
    for (int j = 0; j < 3; ++j) {
      double v = 0.0;
#pragma unroll
      for (int k = 0; k < 4; ++k) v += w[k] * X[k][i] * Y[k][j];
      acc[7 + 3 * i + j] = v;
    }
  // single interleaved butterfly: 16 independent chains, 6 levels
#pragma unroll
  for (int m = 32; m >= 1; m >>= 1)
#pragma unroll
    for (int r = 0; r < 16; ++r) acc[r] += __shfl_xor(acc[r], m, 64);

  double sw = acc[0];
  double rinv = 1.0 / (sw + 1e-8);  // single divide
  double cx[3], cy[3];
#pragma unroll
  for (int i = 0; i < 3; ++i) { cx[i] = acc[1 + i] * rinv; cy[i] = acc[4 + i] * rinv; }
  double H[3][3];
#pragma unroll
  for (int i = 0; i < 3; ++i)
#pragma unroll
    for (int j = 0; j < 3; ++j)
      H[i][j] = acc[7 + 3 * i + j] - cx[i] * acc[4 + j] - acc[1 + i] * cy[j] +
                sw * cx[i] * cy[j];

  double Kq[4][4];
  Kq[0][0] =  H[0][0] + H[1][1] + H[2][2];
  Kq[1][1] =  H[0][0] - H[1][1] - H[2][2];
  Kq[2][2] = -H[0][0] + H[1][1] - H[2][2];
  Kq[3][3] = -H[0][0] - H[1][1] + H[2][2];
  Kq[0][1] = Kq[1][0] = H[1][2] - H[2][1];
  Kq[0][2] = Kq[2][0] = H[2][0] - H[0][2];
  Kq[0][3] = Kq[3][0] = H[0][1] - H[1][0];
  Kq[1][2] = Kq[2][1] = H[0][1] + H[1][0];
  Kq[1][3] = Kq[3][1] = H[0][2] + H[2][0];
  Kq[2][3] = Kq[3][2] = H[1][2] + H[2][1];

  double V[4][4];
  jacobi4(Kq, V);

  // eigenvector of largest eigenvalue (static indexing)
  double bev = Kq[0][0];
  double qw = V[0][0], qx = V[1][0], qy = V[2][0], qz = V[3][0];
#pragma unroll
  for (int i = 1; i < 4; ++i) {
    bool better = Kq[i][i] > bev;
    bev = better ? Kq[i][i] : bev;
    qw = better ? V[0][i] : qw;
    qx = better ? V[1][i] : qx;
    qy = better ? V[2][i] : qy;
    qz = better ? V[3][i] : qz;
  }
  double qn = rsqrt(qw * qw + qx * qx + qy * qy + qz * qz);
  qw *= qn; qx *= qn; qy *= qn; qz *= qn;

  R[0][0] = 1.0 - 2.0 * (qy * qy + qz * qz);
  R[0][1] = 2.0 * (qx * qy - qw * qz);
  R[0][2] = 2.0 * (qx * qz + qw * qy);
  R[1][0] = 2.0 * (qx * qy + qw * qz);
  R[1][1] = 1.0 - 2.0 * (qx * qx + qz * qz);
  R[1][2] = 2.0 * (qy * qz - qw * qx);
  R[2][0] = 2.0 * (qx * qz - qw * qy);
  R[2][1] = 2.0 * (qy * qz + qw * qx);
  R[2][2] = 1.0 - 2.0 * (qx * qx + qy * qy);
#pragma unroll
  for (int i = 0; i < 3; ++i)
    t[i] = cy[i] - (R[i][0] * cx[0] + R[i][1] * cx[1] + R[i][2] * cx[2]);
}

// ---- one wave (64 lanes) per RANSAC candidate m in [0,2048); 4 points/lane.
// Exactness notes:
//  * final procrustes(Xv,Yv,inl_final) always re-fits weights already fit in
//    the loop (inl_final = inl of last improving iter, or inl0), so saving
//    R,t + residuals there makes the final fit free and bit-identical.
//  * early-exit on first non-improving iteration is a fixed point of the
//    reference loop (identical weights -> identical fit -> improved false).
//  * residual compare done in squared form: sq < TH^2 <=> sqrt(sq) < TH
//    (monotone, correctly-rounded sqrt; <=1 ulp boundary equivalence). ----
__global__ __launch_bounds__(64) void pose_fit_kernel(
    const float* __restrict__ kps0, const float* __restrict__ kps1,
    const float* __restrict__ depth0, const float* __restrict__ depth1,
    const float* __restrict__ T01,
    const float* __restrict__ K0, const float* __restrict__ K1,
    const int* __restrict__ sidx, const int* __restrict__ sransac,
    double* __restrict__ oscore, double* __restrict__ olr,
    double* __restrict__ olt) {
  const int m = blockIdx.x;      // candidate (0..2047)
  const int v = m >> 4;          // sample row (0..127), IT_R = 16
  const int b = v >> 4;          // batch (0..7), IT_M = 16
  const int lane = threadIdx.x;  // 0..63

  double Ki0[3][3], Ki1[3][3];
  inv3(K0 + b * 9, Ki0);
  inv3(K1 + b * 9, Ki1);

  // gather + backproject 4 points per lane (f64)
  double X[4][3], Y[4][3];
#pragma unroll
  for (int k = 0; k < 4; ++k) {
    int s = lane + 64 * k;
    int idx = sidx[v * S + s];
    int i0 = idx >> 10;       // idx / NK
    int i1 = idx & (NK - 1);  // idx % NK
    double u0 = (double)kps0[b * 2 * NK + i0];
    double w0 = (double)kps0[b * 2 * NK + NK + i0];
    double d0 = (double)depth0[b * NK + i0];
    double u1 = (double)kps1[b * 2 * NK + i1];
    double w1 = (double)kps1[b * 2 * NK + NK + i1];
    double d1 = (double)depth1[b * NK + i1];
#pragma unroll
    for (int i = 0; i < 3; ++i) {
      X[k][i] = d0 * (Ki0[i][0] * u0 + Ki0[i][1] * w0 + Ki0[i][2]);
      Y[k][i] = d1 * (Ki1[i][0] * u1 + Ki1[i][1] * w1 + Ki1[i][2]);
    }
  }

  // initial inlier mask from the 5 ransac seed indices
  int r5[5];
#pragma unroll
  for (int c = 0; c < 5; ++c) r5[c] = sransac[m * 5 + c];
  double w[4];
#pragma unroll
  for (int k = 0; k < 4; ++k) {
    int s = lane + 64 * k;
    double val = 0.0;
#pragma unroll
    for (int c = 0; c < 5; ++c) val = (r5[c] == s) ? 1.0 : val;
    w[k] = val;
  }

  double pre = 5.0;  // NC
  double R[3][3], t[3];
  double Rf[3][3], tf[3];  // fit corresponding to inl_final
  double sqf[4];           // squared residuals under Rf,tf (for the score)
  for (int it = 0; it < NREF; ++it) {
    fit(X, Y, w, R, t);
    double ref[4], sq[4];
    double rs = 0.0;
#pragma unroll
    for (int k = 0; k < 4; ++k) {
      double e0 = Y[k][0] - (R[0][0] * X[k][0] + R[0][1] * X[k][1] + R[0][2] * X[k][2] + t[0]);
      double e1 = Y[k][1] - (R[1][0] * X[k][0] + R[1][1] * X[k][1] + R[1][2] * X[k][2] + t[1]);
      double e2 = Y[k][2] - (R[2][0] * X[k][0] + R[2][1] * X[k][1] + R[2][2] * X[k][2] + t[2]);
      sq[k] = e0 * e0 + e1 * e1 + e2 * e2;
      ref[k] = (sq[k] < 0.0225) ? 1.0 : 0.0;  // (r < 0.15)
      rs += ref[k];
    }
    double refsum = wsum(rs);          // lane-uniform
    bool improved = refsum > pre;
    if (it == 0 || improved) {         // this fit is (currently) the final one
#pragma unroll
      for (int i = 0; i < 3; ++i) {
#pragma unroll
        for (int j = 0; j < 3; ++j) Rf[i][j] = R[i][j];
        tf[i] = t[i];
      }
#pragma unroll
      for (int k = 0; k < 4; ++k) sqf[k] = sq[k];
    }
    if (improved) {
      pre = refsum;
#pragma unroll
      for (int k = 0; k < 4; ++k) w[k] = ref[k];
    } else {
      break;  // exact fixed point (see header comment)
    }
  }

  // smooth score from saved residuals (f32 tail: no thresholds downstream)
  float sc = 0.0f;
#pragma unroll
  for (int k = 0; k < 4; ++k) {
    float r = sqrtf((float)sqf[k]);
    float xar = 5.0f * (1.0f - r * (1.0f / 0.15f));  // BETA*(1-r/TH)
    sc += 1.0f / (1.0f + __expf(-xar));
  }
  float score = wsumf(sc);

  // pose errors vs ground truth T_0to1[b] (smooth path -> f32 transcendentals)
  const float* Tb = T01 + b * 16;
  double tr = 0.0;
#pragma unroll
  for (int i = 0; i < 3; ++i)
#pragma unroll
    for (int j = 0; j < 3; ++j) tr += Rf[i][j] * (double)Tb[i * 4 + j];
  double xcl = 0.5 * (tr - 1.0);
  const double lo = -1.0 + 1e-6, hi = 1.0 - 1e-6;
  xcl = xcl < lo ? lo : (xcl > hi ? hi : xcl);
  float rot_err = acosf((float)xcl) * (float)(180.0 / M_PI);
  double te0 = tf[0] - (double)Tb[3];
  double te1 = tf[1] - (double)Tb[7];
  double te2 = tf[2] - (double)Tb[11];
  float terr = sqrtf((float)(te0 * te0 + te1 * te1 + te2 * te2));
  float lr = 45.0f * tanhf(rot_err * (1.0f / 45.0f));  // MAX_ROT
  float lt = tanhf(terr);                              // MAX_TRANS = 1

  if (lane == 0) {
    oscore[m] = (double)score;
    olr[m] = (double)lr;
    olt[m] = (double)lt;
  }
}

// ---- softmax(score/TEMP) over IT_R=16, weighted losses, mean over IT_M=16 ----
// Output is FLOAT32, flat (2, B, 1) = [rot x8, trans x8].
__global__ __launch_bounds__(128) void pose_reduce_kernel(
    const double* __restrict__ oscore, const double* __restrict__ olr,
    const double* __restrict__ olt, float* __restrict__ out) {
  __shared__ double slr[BV], slt[BV];
  int k = threadIdx.x;  // bv index 0..127
  double sc[16];
  double mx = -1e300;
#pragma unroll
  for (int r = 0; r < 16; ++r) {
    sc[r] = oscore[k * 16 + r];
    mx = fmax(mx, sc[r]);
  }
  double den = 0.0, wl = 0.0, wt = 0.0;
#pragma unroll
  for (int r = 0; r < 16; ++r) {
    double e = (double)__expf((float)((sc[r] - mx) * 0.1));  // /TEMP
    den += e;
    wl += e * olr[k * 16 + r];
    wt += e * olt[k * 16 + r];
  }
  slr[k] = wl / den;
  slt[k] = wt / den;
  __syncthreads();
  if (k < 8) {
    double a = 0.0, c = 0.0;
#pragma unroll
    for (int i = 0; i < 16; ++i) {
      a += slr[k * 16 + i];
      c += slt[k * 16 + i];
    }
    out[k]     = (float)(a / 16.0);  // losses_rot,   (2,B,1) flat
    out[8 + k] = (float)(c / 16.0);  // losses_trans
  }
}

}  // namespace mp

extern "C" void kernel_launch(void* const* d_in, const int* in_sizes, int n_in,
                              void* d_out, int out_size, void* d_ws, size_t ws_size,
                              hipStream_t stream) {
  // input order per setup_inputs(): 0 matches (unused), 1 kps0, 2 kps1,
  // 3 depth0, 4 depth1, 5 T_0to1, 6 K_color0, 7 K_color1, 8/9 Kori (unused),
  // 10 sampled_idx, 11 sampled_idx_ransac
  const float* kps0   = (const float*)d_in[1];
  const float* kps1   = (const float*)d_in[2];
  const float* depth0 = (const float*)d_in[3];
  const float* depth1 = (const float*)d_in[4];
  const float* T01    = (const float*)d_in[5];
  const float* K0     = (const float*)d_in[6];
  const float* K1     = (const float*)d_in[7];
  const int* sidx     = (const int*)d_in[10];
  const int* srans    = (const int*)d_in[11];

  double* ws     = (double*)d_ws;  // 3 * 2048 * 8B = 48 KB scratch
  double* oscore = ws;
  double* olr    = ws + mp::BIV;
  double* olt    = ws + 2 * mp::BIV;

  mp::pose_fit_kernel<<<mp::BIV, 64, 0, stream>>>(
      kps0, kps1, depth0, depth1, T01, K0, K1, sidx, srans, oscore, olr, olt);
  mp::pose_reduce_kernel<<<1, 128, 0, stream>>>(
      oscore, olr, olt, (float*)d_out);
}

// Round 5
// 19.244 us; speedup vs baseline: 3.0583x; 1.3135x over previous
//
#include <hip/hip_runtime.h>
#include <hip/hip_bf16.h>
#include <math.h>

#ifndef M_PI
#define M_PI 3.14159265358979323846
#endif

namespace mp {

constexpr int NK   = 1024;
constexpr int S    = 256;
constexpr int NREF = 4;
constexpr int BV   = 128;   // B * IT_M
constexpr int BIV  = 2048;  // BV * IT_R

// ---- wave-wide (64-lane) all-reduce sum, identical result on all lanes ----
__device__ inline double wsum(double v) {
#pragma unroll
  for (int m = 32; m >= 1; m >>= 1) v += __shfl_xor(v, m, 64);
  return v;
}
__device__ inline float wsumf(float v) {
#pragma unroll
  for (int m = 32; m >= 1; m >>= 1) v += __shfl_xor(v, m, 64);
  return v;
}

// ---- general 3x3 inverse (adjugate / det), f64 ----
__device__ inline void inv3(const float* __restrict__ K, double Ki[3][3]) {
  double a = K[0], b = K[1], c = K[2];
  double d = K[3], e = K[4], f = K[5];
  double g = K[6], h = K[7], i = K[8];
  double A  =  (e * i - f * h);
  double Bm = -(d * i - f * g);
  double C  =  (d * h - e * g);
  double det = a * A + b * Bm + c * C;
  double inv = 1.0 / det;
  Ki[0][0] = A * inv;  Ki[0][1] = -(b * i - c * h) * inv;  Ki[0][2] =  (b * f - c * e) * inv;
  Ki[1][0] = Bm * inv; Ki[1][1] =  (a * i - c * g) * inv;  Ki[1][2] = -(a * f - c * d) * inv;
  Ki[2][0] = C * inv;  Ki[2][1] = -(a * h - b * g) * inv;  Ki[2][2] =  (a * e - b * d) * inv;
}

__device__ inline double det3(double a, double b, double c,
                              double d, double e, double f,
                              double g, double h, double i) {
  return a * (e * i - f * h) - b * (d * i - f * g) + c * (d * h - e * g);
}

// ---- weighted Procrustes: Y ~= R X + t. Horn/Davenport quaternion method,
//      solved QUEST-style (closed-form char poly + Newton-from-above for
//      lambda_max + adjugate eigenvector). Equivalent optimum to Kabsch
//      V diag(1,1,det) U^T. One-pass moment reduction:
//      H = S - cx*sy^T - sx*cy^T + sw*cx*cy^T (reproduces reference's
//      sw+1e-8 epsilon semantics). All lanes hold identical reduced values,
//      so every branch below is wave-uniform. ----
__device__ inline void fit(const double X[4][3], const double Y[4][3],
                           const double w[4], double R[3][3], double t[3]) {
  // acc: [0]=sw, [1..3]=sx, [4..6]=sy, [7+3i+j]=Sxy[i][j]
  double acc[16];
  acc[0] = w[0] + w[1] + w[2] + w[3];
#pragma unroll
  for (int i = 0; i < 3; ++i) {
    acc[1 + i] = w[0] * X[0][i] + w[1] * X[1][i] + w[2] * X[2][i] + w[3] * X[3][i];
    acc[4 + i] = w[0] * Y[0][i] + w[1] * Y[1][i] + w[2] * Y[2][i] + w[3] * Y[3][i];
  }
#pragma unroll
  for (int i = 0; i < 3; ++i)
#pragma unroll
    for (int j = 0; j < 3; ++j) {
      double v = 0.0;
#pragma unroll
      for (int k = 0; k < 4; ++k) v += w[k] * X[k][i] * Y[k][j];
      acc[7 + 3 * i + j] = v;
    }
  // single interleaved butterfly: 16 independent chains, 6 levels
#pragma unroll
  for (int m = 32; m >= 1; m >>= 1)
#pragma unroll
    for (int r = 0; r < 16; ++r) acc[r] += __shfl_xor(acc[r], m, 64);

  double sw = acc[0];
  double rinv = 1.0 / (sw + 1e-8);  // single divide
  double cx[3], cy[3];
#pragma unroll
  for (int i = 0; i < 3; ++i) { cx[i] = acc[1 + i] * rinv; cy[i] = acc[4 + i] * rinv; }
  double H[3][3];
#pragma unroll
  for (int i = 0; i < 3; ++i)
#pragma unroll
    for (int j = 0; j < 3; ++j)
      H[i][j] = acc[7 + 3 * i + j] - cx[i] * acc[4 + j] - acc[1 + i] * cy[j] +
                sw * cx[i] * cy[j];

  // Horn's K (symmetric, TRACELESS), 10 unique entries, q = (w,x,y,z)
  double k00 =  H[0][0] + H[1][1] + H[2][2];
  double k11 =  H[0][0] - H[1][1] - H[2][2];
  double k22 = -H[0][0] + H[1][1] - H[2][2];
  double k33 = -H[0][0] - H[1][1] + H[2][2];
  double k01 = H[1][2] - H[2][1];
  double k02 = H[2][0] - H[0][2];
  double k03 = H[0][1] - H[1][0];
  double k12 = H[0][1] + H[1][0];
  double k13 = H[0][2] + H[2][0];
  double k23 = H[1][2] + H[2][1];

  // char poly p(l) = l^4 + e2 l^2 - e3 l + e4  (trace = 0)
  double e2 = (k00 * k11 - k01 * k01) + (k00 * k22 - k02 * k02) +
              (k00 * k33 - k03 * k03) + (k11 * k22 - k12 * k12) +
              (k11 * k33 - k13 * k13) + (k22 * k33 - k23 * k23);
  double e3 = det3(k00, k01, k02, k01, k11, k12, k02, k12, k22) +
              det3(k00, k01, k03, k01, k11, k13, k03, k13, k33) +
              det3(k00, k02, k03, k02, k22, k23, k03, k23, k33) +
              det3(k11, k12, k13, k12, k22, k23, k13, k23, k33);
  // e4 = det(K), cofactor expansion along row 0
  double M00 = det3(k11, k12, k13, k12, k22, k23, k13, k23, k33);
  double M01 = det3(k01, k12, k13, k02, k22, k23, k03, k23, k33);
  double M02 = det3(k01, k11, k13, k02, k12, k23, k03, k13, k33);
  double M03 = det3(k01, k11, k12, k02, k12, k22, k03, k13, k23);
  double e4 = k00 * M00 - k01 * M01 + k02 * M02 - k03 * M03;

  // upper bound for lambda_max: min(Gershgorin, Frobenius); ||K||F^2 = -2 e2
  double g0 = k00 + fabs(k01) + fabs(k02) + fabs(k03);
  double g1 = k11 + fabs(k01) + fabs(k12) + fabs(k13);
  double g2 = k22 + fabs(k02) + fabs(k12) + fabs(k23);
  double g3 = k33 + fabs(k03) + fabs(k13) + fabs(k23);
  double gersh = fmax(fmax(g0, g1), fmax(g2, g3));
  double frob = sqrt(fmax(-2.0 * e2, 0.0));
  double l0 = fmax(fmin(gersh, frob), 0.0);

  // Newton from above: monotone (p convex and >=0 on [lmax, l0]); all lanes
  // identical -> uniform break. ~6-8 iterations to machine precision.
  double lam = l0;
  for (int it = 0; it < 20; ++it) {
    double lam2 = lam * lam;
    double p = ((lam2 + e2) * lam - e3) * lam + e4;
    double pp = (4.0 * lam2 + 2.0 * e2) * lam - e3;
    double step = p / pp;
    lam -= step;
    if (!(step > 1e-13 * l0)) break;  // also breaks on NaN/0-step
  }

  // eigenvector = max-|diagonal| column of adj(K - lam*I)  (= kappa*q*q^T)
  double m00 = k00 - lam, m11 = k11 - lam, m22 = k22 - lam, m33 = k33 - lam;
  double c00 = det3(m11, k12, k13, k12, m22, k23, k13, k23, m33);
  double c01 = -det3(k01, k12, k13, k02, m22, k23, k03, k23, m33);
  double c02 = det3(k01, m11, k13, k02, k12, k23, k03, k13, m33);
  double c03 = -det3(k01, m11, k12, k02, k12, m22, k03, k13, k23);
  double c11 = det3(m00, k02, k03, k02, m22, k23, k03, k23, m33);
  double c12 = -det3(m00, k01, k03, k02, k12, k23, k03, k13, m33);
  double c13 = det3(m00, k01, k02, k02, k12, m22, k03, k13, k23);
  double c22 = det3(m00, k01, k03, k01, m11, k13, k03, k13, m33);
  double c23 = -det3(m00, k01, k02, k01, m11, k12, k03, k13, k23);
  double c33 = det3(m00, k01, k02, k01, m11, k12, k02, k12, m22);

  double a0 = fabs(c00), a1 = fabs(c11), a2 = fabs(c22), a3 = fabs(c33);
  double q0 = c00, q1 = c01, q2 = c02, q3 = c03, bb = a0;
  bool t1 = a1 > bb; bb = t1 ? a1 : bb;
  q0 = t1 ? c01 : q0; q1 = t1 ? c11 : q1; q2 = t1 ? c12 : q2; q3 = t1 ? c13 : q3;
  bool t2 = a2 > bb; bb = t2 ? a2 : bb;
  q0 = t2 ? c02 : q0; q1 = t2 ? c12 : q1; q2 = t2 ? c22 : q2; q3 = t2 ? c23 : q3;
  bool t3 = a3 > bb;
  q0 = t3 ? c03 : q0; q1 = t3 ? c13 : q1; q2 = t3 ? c23 : q2; q3 = t3 ? c33 : q3;

  double n2 = q0 * q0 + q1 * q1 + q2 * q2 + q3 * q3;
  bool ok = n2 > 1e-250;  // degenerate (K ~ 0) -> R = I, matches SVD(0)
  double qn = rsqrt(ok ? n2 : 1.0);
  double qw = ok ? q0 * qn : 1.0;
  double qx = ok ? q1 * qn : 0.0;
  double qy = ok ? q2 * qn : 0.0;
  double qz = ok ? q3 * qn : 0.0;

  R[0][0] = 1.0 - 2.0 * (qy * qy + qz * qz);
  R[0][1] = 2.0 * (qx * qy - qw * qz);
  R[0][2] = 2.0 * (qx * qz + qw * qy);
  R[1][0] = 2.0 * (qx * qy + qw * qz);
  R[1][1] = 1.0 - 2.0 * (qx * qx + qz * qz);
  R[1][2] = 2.0 * (qy * qz - qw * qx);
  R[2][0] = 2.0 * (qx * qz - qw * qy);
  R[2][1] = 2.0 * (qy * qz + qw * qx);
  R[2][2] = 1.0 - 2.0 * (qx * qx + qy * qy);
#pragma unroll
  for (int i = 0; i < 3; ++i)
    t[i] = cy[i] - (R[i][0] * cx[0] + R[i][1] * cx[1] + R[i][2] * cx[2]);
}

// ---- one wave (64 lanes) per RANSAC candidate m in [0,2048); 4 points/lane.
// Exactness notes:
//  * final procrustes(Xv,Yv,inl_final) always re-fits weights already fit in
//    the loop (inl_final = inl of last improving iter, or inl0), so saving
//    R,t + residuals there makes the final fit free and bit-identical.
//  * early-exit on first non-improving iteration is a fixed point of the
//    reference loop (identical weights -> identical fit -> improved false).
//  * residual compare done in squared form: sq < TH^2 <=> sqrt(sq) < TH. ----
__global__ __launch_bounds__(64) void pose_fit_kernel(
    const float* __restrict__ kps0, const float* __restrict__ kps1,
    const float* __restrict__ depth0, const float* __restrict__ depth1,
    const float* __restrict__ T01,
    const float* __restrict__ K0, const float* __restrict__ K1,
    const int* __restrict__ sidx, const int* __restrict__ sransac,
    double* __restrict__ oscore, double* __restrict__ olr,
    double* __restrict__ olt) {
  const int m = blockIdx.x;      // candidate (0..2047)
  const int v = m >> 4;          // sample row (0..127), IT_R = 16
  const int b = v >> 4;          // batch (0..7), IT_M = 16
  const int lane = threadIdx.x;  // 0..63

  double Ki0[3][3], Ki1[3][3];
  inv3(K0 + b * 9, Ki0);
  inv3(K1 + b * 9, Ki1);

  // gather + backproject 4 points per lane (f64)
  double X[4][3], Y[4][3];
#pragma unroll
  for (int k = 0; k < 4; ++k) {
    int s = lane + 64 * k;
    int idx = sidx[v * S + s];
    int i0 = idx >> 10;       // idx / NK
    int i1 = idx & (NK - 1);  // idx % NK
    double u0 = (double)kps0[b * 2 * NK + i0];
    double w0 = (double)kps0[b * 2 * NK + NK + i0];
    double d0 = (double)depth0[b * NK + i0];
    double u1 = (double)kps1[b * 2 * NK + i1];
    double w1 = (double)kps1[b * 2 * NK + NK + i1];
    double d1 = (double)depth1[b * NK + i1];
#pragma unroll
    for (int i = 0; i < 3; ++i) {
      X[k][i] = d0 * (Ki0[i][0] * u0 + Ki0[i][1] * w0 + Ki0[i][2]);
      Y[k][i] = d1 * (Ki1[i][0] * u1 + Ki1[i][1] * w1 + Ki1[i][2]);
    }
  }

  // initial inlier mask from the 5 ransac seed indices
  int r5[5];
#pragma unroll
  for (int c = 0; c < 5; ++c) r5[c] = sransac[m * 5 + c];
  double w[4];
#pragma unroll
  for (int k = 0; k < 4; ++k) {
    int s = lane + 64 * k;
    double val = 0.0;
#pragma unroll
    for (int c = 0; c < 5; ++c) val = (r5[c] == s) ? 1.0 : val;
    w[k] = val;
  }

  double pre = 5.0;  // NC
  double R[3][3], t[3];
  double Rf[3][3], tf[3];  // fit corresponding to inl_final
  double sqf[4];           // squared residuals under Rf,tf (for the score)
  for (int it = 0; it < NREF; ++it) {
    fit(X, Y, w, R, t);
    double ref[4], sq[4];
    double rs = 0.0;
#pragma unroll
    for (int k = 0; k < 4; ++k) {
      double e0 = Y[k][0] - (R[0][0] * X[k][0] + R[0][1] * X[k][1] + R[0][2] * X[k][2] + t[0]);
      double e1 = Y[k][1] - (R[1][0] * X[k][0] + R[1][1] * X[k][1] + R[1][2] * X[k][2] + t[1]);
      double e2 = Y[k][2] - (R[2][0] * X[k][0] + R[2][1] * X[k][1] + R[2][2] * X[k][2] + t[2]);
      sq[k] = e0 * e0 + e1 * e1 + e2 * e2;
      ref[k] = (sq[k] < 0.0225) ? 1.0 : 0.0;  // (r < 0.15)
      rs += ref[k];
    }
    double refsum = wsum(rs);          // lane-uniform
    bool improved = refsum > pre;
    if (it == 0 || improved) {         // this fit is (currently) the final one
#pragma unroll
      for (int i = 0; i < 3; ++i) {
#pragma unroll
        for (int j = 0; j < 3; ++j) Rf[i][j] = R[i][j];
        tf[i] = t[i];
      }
#pragma unroll
      for (int k = 0; k < 4; ++k) sqf[k] = sq[k];
    }
    if (improved) {
      pre = refsum;
#pragma unroll
      for (int k = 0; k < 4; ++k) w[k] = ref[k];
    } else {
      break;  // exact fixed point (see header comment)
    }
  }

  // smooth score from saved residuals (f32 tail: no thresholds downstream)
  float sc = 0.0f;
#pragma unroll
  for (int k = 0; k < 4; ++k) {
    float r = sqrtf((float)sqf[k]);
    float xar = 5.0f * (1.0f - r * (1.0f / 0.15f));  // BETA*(1-r/TH)
    sc += 1.0f / (1.0f + __expf(-xar));
  }
  float score = wsumf(sc);

  // pose errors vs ground truth T_0to1[b] (smooth path -> f32 transcendentals)
  const float* Tb = T01 + b * 16;
  double tr = 0.0;
#pragma unroll
  for (int i = 0; i < 3; ++i)
#pragma unroll
    for (int j = 0; j < 3; ++j) tr += Rf[i][j] * (double)Tb[i * 4 + j];
  double xcl = 0.5 * (tr - 1.0);
  const double lo = -1.0 + 1e-6, hi = 1.0 - 1e-6;
  xcl = xcl < lo ? lo : (xcl > hi ? hi : xcl);
  float rot_err = acosf((float)xcl) * (float)(180.0 / M_PI);
  double te0 = tf[0] - (double)Tb[3];
  double te1 = tf[1] - (double)Tb[7];
  double te2 = tf[2] - (double)Tb[11];
  float terr = sqrtf((float)(te0 * te0 + te1 * te1 + te2 * te2));
  float lr = 45.0f * tanhf(rot_err * (1.0f / 45.0f));  // MAX_ROT
  float lt = tanhf(terr);                              // MAX_TRANS = 1

  if (lane == 0) {
    oscore[m] = (double)score;
    olr[m] = (double)lr;
    olt[m] = (double)lt;
  }
}

// ---- softmax(score/TEMP) over IT_R=16, weighted losses, mean over IT_M=16 ----
// Output is FLOAT32, flat (2, B, 1) = [rot x8, trans x8].
__global__ __launch_bounds__(128) void pose_reduce_kernel(
    const double* __restrict__ oscore, const double* __restrict__ olr,
    const double* __restrict__ olt, float* __restrict__ out) {
  __shared__ double slr[BV], slt[BV];
  int k = threadIdx.x;  // bv index 0..127
  double sc[16];
  double mx = -1e300;
#pragma unroll
  for (int r = 0; r < 16; ++r) {
    sc[r] = oscore[k * 16 + r];
    mx = fmax(mx, sc[r]);
  }
  double den = 0.0, wl = 0.0, wt = 0.0;
#pragma unroll
  for (int r = 0; r < 16; ++r) {
    double e = (double)__expf((float)((sc[r] - mx) * 0.1));  // /TEMP
    den += e;
    wl += e * olr[k * 16 + r];
    wt += e * olt[k * 16 + r];
  }
  slr[k] = wl / den;
  slt[k] = wt / den;
  __syncthreads();
  if (k < 8) {
    double a = 0.0, c = 0.0;
#pragma unroll
    for (int i = 0; i < 16; ++i) {
      a += slr[k * 16 + i];
      c += slt[k * 16 + i];
    }
    out[k]     = (float)(a / 16.0);  // losses_rot,   (2,B,1) flat
    out[8 + k] = (float)(c / 16.0);  // losses_trans
  }
}

}  // namespace mp

extern "C" void kernel_launch(void* const* d_in, const int* in_sizes, int n_in,
                              void* d_out, int out_size, void* d_ws, size_t ws_size,
                              hipStream_t stream) {
  // input order per setup_inputs(): 0 matches (unused), 1 kps0, 2 kps1,
  // 3 depth0, 4 depth1, 5 T_0to1, 6 K_color0, 7 K_color1, 8/9 Kori (unused),
  // 10 sampled_idx, 11 sampled_idx_ransac
  const float* kps0   = (const float*)d_in[1];
  const float* kps1   = (const float*)d_in[2];
  const float* depth0 = (const float*)d_in[3];
  const float* depth1 = (const float*)d_in[4];
  const float* T01    = (const float*)d_in[5];
  const float* K0     = (const float*)d_in[6];
  const float* K1     = (const float*)d_in[7];
  const int* sidx     = (const int*)d_in[10];
  const int* srans    = (const int*)d_in[11];

  double* ws     = (double*)d_ws;  // 3 * 2048 * 8B = 48 KB scratch
  double* oscore = ws;
  double* olr    = ws + mp::BIV;
  double* olt    = ws + 2 * mp::BIV;

  mp::pose_fit_kernel<<<mp::BIV, 64, 0, stream>>>(
      kps0, kps1, depth0, depth1, T01, K0, K1, sidx, srans, oscore, olr, olt);
  mp::pose_reduce_kernel<<<1, 128, 0, stream>>>(
      oscore, olr, olt, (float*)d_out);
}

// Round 6
// 17.011 us; speedup vs baseline: 3.4597x; 1.1313x over previous
//
#include <hip/hip_runtime.h>
#include <hip/hip_bf16.h>
#include <math.h>

#ifndef M_PI
#define M_PI 3.14159265358979323846
#endif

namespace mp {

constexpr int NK   = 1024;
constexpr int S    = 256;
constexpr int NREF = 4;
constexpr int BV   = 128;   // B * IT_M
constexpr int BIV  = 2048;  // BV * IT_R

// ---- 32-lane-group all-reduce sum (masks 1..16 stay within each half-wave);
//      identical result on all lanes of the group ----
template <typename T>
__device__ inline T gsum(T v) {
#pragma unroll
  for (int mk = 16; mk >= 1; mk >>= 1) v += __shfl_xor(v, mk, 64);
  return v;
}

// ---- general 3x3 inverse (adjugate / det), f64 ----
__device__ inline void inv3(const float* __restrict__ K, double Ki[3][3]) {
  double a = K[0], b = K[1], c = K[2];
  double d = K[3], e = K[4], f = K[5];
  double g = K[6], h = K[7], i = K[8];
  double A  =  (e * i - f * h);
  double Bm = -(d * i - f * g);
  double C  =  (d * h - e * g);
  double det = a * A + b * Bm + c * C;
  double inv = 1.0 / det;
  Ki[0][0] = A * inv;  Ki[0][1] = -(b * i - c * h) * inv;  Ki[0][2] =  (b * f - c * e) * inv;
  Ki[1][0] = Bm * inv; Ki[1][1] =  (a * i - c * g) * inv;  Ki[1][2] = -(a * f - c * d) * inv;
  Ki[2][0] = C * inv;  Ki[2][1] = -(a * h - b * g) * inv;  Ki[2][2] =  (a * e - b * d) * inv;
}

__device__ inline double det3(double a, double b, double c,
                              double d, double e, double f,
                              double g, double h, double i) {
  return a * (e * i - f * h) - b * (d * i - f * g) + c * (d * h - e * g);
}

// ---- weighted Procrustes for one 32-lane group (8 points/lane, weights as
//      an 8-bit mask). Horn/Davenport quaternion via QUEST closed form.
//      Moments f64 (bit-safe decisions downstream); Newton split f32->f64.
//      All lanes of a group hold identical reduced values -> QUEST runs
//      SIMT-shared across the wave's 2 groups. ----
__device__ inline void fitq(const double X[8][3], const double Y[8][3],
                            unsigned wm, double R[3][3], double t[3]) {
  // acc: [0]=sw, [1..3]=sx, [4..6]=sy, [7+3i+j]=Sxy[i][j]
  double acc[16];
  acc[0] = (double)__popc(wm);
#pragma unroll
  for (int r = 1; r < 16; ++r) acc[r] = 0.0;
#pragma unroll
  for (int k = 0; k < 8; ++k) {
    bool w = (wm >> k) & 1u;
    double x0 = w ? X[k][0] : 0.0, x1 = w ? X[k][1] : 0.0, x2 = w ? X[k][2] : 0.0;
    double y0 = Y[k][0], y1 = Y[k][1], y2 = Y[k][2];
    acc[1] += x0; acc[2] += x1; acc[3] += x2;
    acc[4] += w ? y0 : 0.0; acc[5] += w ? y1 : 0.0; acc[6] += w ? y2 : 0.0;
    acc[7]  += x0 * y0; acc[8]  += x0 * y1; acc[9]  += x0 * y2;
    acc[10] += x1 * y0; acc[11] += x1 * y1; acc[12] += x1 * y2;
    acc[13] += x2 * y0; acc[14] += x2 * y1; acc[15] += x2 * y2;
  }
  // group butterfly: 16 independent chains, 5 levels (within 32-lane group)
#pragma unroll
  for (int mk = 16; mk >= 1; mk >>= 1)
#pragma unroll
    for (int r = 0; r < 16; ++r) acc[r] += __shfl_xor(acc[r], mk, 64);

  double sw = acc[0];
  double rinv = 1.0 / (sw + 1e-8);  // reference's +1e-8 epsilon
  double cx[3], cy[3];
#pragma unroll
  for (int i = 0; i < 3; ++i) { cx[i] = acc[1 + i] * rinv; cy[i] = acc[4 + i] * rinv; }
  double H[3][3];
#pragma unroll
  for (int i = 0; i < 3; ++i)
#pragma unroll
    for (int j = 0; j < 3; ++j)
      H[i][j] = acc[7 + 3 * i + j] - cx[i] * acc[4 + j] - acc[1 + i] * cy[j] +
                sw * cx[i] * cy[j];

  // Horn's K (symmetric, traceless), q = (w,x,y,z)
  double k00 =  H[0][0] + H[1][1] + H[2][2];
  double k11 =  H[0][0] - H[1][1] - H[2][2];
  double k22 = -H[0][0] + H[1][1] - H[2][2];
  double k33 = -H[0][0] - H[1][1] + H[2][2];
  double k01 = H[1][2] - H[2][1];
  double k02 = H[2][0] - H[0][2];
  double k03 = H[0][1] - H[1][0];
  double k12 = H[0][1] + H[1][0];
  double k13 = H[0][2] + H[2][0];
  double k23 = H[1][2] + H[2][1];

  // char poly p(l) = l^4 + e2 l^2 - e3 l + e4
  double e2 = (k00 * k11 - k01 * k01) + (k00 * k22 - k02 * k02) +
              (k00 * k33 - k03 * k03) + (k11 * k22 - k12 * k12) +
              (k11 * k33 - k13 * k13) + (k22 * k33 - k23 * k23);
  double e3 = det3(k00, k01, k02, k01, k11, k12, k02, k12, k22) +
              det3(k00, k01, k03, k01, k11, k13, k03, k13, k33) +
              det3(k00, k02, k03, k02, k22, k23, k03, k23, k33) +
              det3(k11, k12, k13, k12, k22, k23, k13, k23, k33);
  double M00 = det3(k11, k12, k13, k12, k22, k23, k13, k23, k33);
  double M01 = det3(k01, k12, k13, k02, k22, k23, k03, k23, k33);
  double M02 = det3(k01, k11, k13, k02, k12, k23, k03, k13, k33);
  double M03 = det3(k01, k11, k12, k02, k12, k22, k03, k13, k23);
  double e4 = k00 * M00 - k01 * M01 + k02 * M02 - k03 * M03;

  // upper bound: min(Gershgorin, Frobenius); ||K||F^2 = -2 e2
  double g0 = k00 + fabs(k01) + fabs(k02) + fabs(k03);
  double g1 = k11 + fabs(k01) + fabs(k12) + fabs(k13);
  double g2 = k22 + fabs(k02) + fabs(k12) + fabs(k23);
  double g3 = k33 + fabs(k03) + fabs(k13) + fabs(k23);
  double gersh = fmax(fmax(g0, g1), fmax(g2, g3));
  double frob = sqrt(fmax(-2.0 * e2, 0.0));
  double l0 = fmax(fmin(gersh, frob), 0.0);

  // Newton: 10 cheap f32 iterations (monotone from above; converges to
  // ~1e-7 rel), then 3 f64 polish iterations (quadratic -> machine eps).
  // Degenerate K~0: 0/0 -> NaN -> caught by the n2 guard below (R = I).
  float e2f = (float)e2, e3f = (float)e3, e4f = (float)e4;
  float lamf = (float)l0;
#pragma unroll
  for (int i = 0; i < 10; ++i) {
    float l2 = lamf * lamf;
    float p  = ((l2 + e2f) * lamf - e3f) * lamf + e4f;
    float pp = (4.0f * l2 + 2.0f * e2f) * lamf - e3f;
    lamf -= p / pp;
  }
  double lam = (double)lamf;
#pragma unroll
  for (int i = 0; i < 3; ++i) {
    double l2 = lam * lam;
    double p  = ((l2 + e2) * lam - e3) * lam + e4;
    double pp = (4.0 * l2 + 2.0 * e2) * lam - e3;
    lam -= p / pp;
  }

  // eigenvector = max-|diagonal| column of adj(K - lam*I) (= kappa*q*q^T)
  double m00 = k00 - lam, m11 = k11 - lam, m22 = k22 - lam, m33 = k33 - lam;
  double c00 = det3(m11, k12, k13, k12, m22, k23, k13, k23, m33);
  double c01 = -det3(k01, k12, k13, k02, m22, k23, k03, k23, m33);
  double c02 = det3(k01, m11, k13, k02, k12, k23, k03, k13, m33);
  double c03 = -det3(k01, m11, k12, k02, k12, m22, k03, k13, k23);
  double c11 = det3(m00, k02, k03, k02, m22, k23, k03, k23, m33);
  double c12 = -det3(m00, k01, k03, k02, k12, k23, k03, k13, m33);
  double c13 = det3(m00, k01, k02, k02, k12, m22, k03, k13, k23);
  double c22 = det3(m00, k01, k03, k01, m11, k13, k03, k13, m33);
  double c23 = -det3(m00, k01, k02, k01, m11, k12, k03, k13, k23);
  double c33 = det3(m00, k01, k02, k01, m11, k12, k02, k12, m22);

  double a0 = fabs(c00), a1 = fabs(c11), a2 = fabs(c22), a3 = fabs(c33);
  double q0 = c00, q1 = c01, q2 = c02, q3 = c03, bb = a0;
  bool t1 = a1 > bb; bb = t1 ? a1 : bb;
  q0 = t1 ? c01 : q0; q1 = t1 ? c11 : q1; q2 = t1 ? c12 : q2; q3 = t1 ? c13 : q3;
  bool t2 = a2 > bb; bb = t2 ? a2 : bb;
  q0 = t2 ? c02 : q0; q1 = t2 ? c12 : q1; q2 = t2 ? c22 : q2; q3 = t2 ? c23 : q3;
  bool t3 = a3 > bb;
  q0 = t3 ? c03 : q0; q1 = t3 ? c13 : q1; q2 = t3 ? c23 : q2; q3 = t3 ? c33 : q3;

  double n2 = q0 * q0 + q1 * q1 + q2 * q2 + q3 * q3;
  bool ok = n2 > 1e-250;  // degenerate -> R = I (matches SVD(0) behavior)
  double qn = rsqrt(ok ? n2 : 1.0);
  double qw = ok ? q0 * qn : 1.0;
  double qx = ok ? q1 * qn : 0.0;
  double qy = ok ? q2 * qn : 0.0;
  double qz = ok ? q3 * qn : 0.0;

  R[0][0] = 1.0 - 2.0 * (qy * qy + qz * qz);
  R[0][1] = 2.0 * (qx * qy - qw * qz);
  R[0][2] = 2.0 * (qx * qz + qw * qy);
  R[1][0] = 2.0 * (qx * qy + qw * qz);
  R[1][1] = 1.0 - 2.0 * (qx * qx + qz * qz);
  R[1][2] = 2.0 * (qy * qz - qw * qx);
  R[2][0] = 2.0 * (qx * qz - qw * qy);
  R[2][1] = 2.0 * (qy * qz + qw * qx);
  R[2][2] = 1.0 - 2.0 * (qx * qx + qy * qy);
#pragma unroll
  for (int i = 0; i < 3; ++i)
    t[i] = cy[i] - (R[i][0] * cx[0] + R[i][1] * cx[1] + R[i][2] * cx[2]);
}

// ---- TWO candidates per wave: group = lane>>5, 8 points/lane.
// Candidates 2k and 2k+1 always share sample row v = m>>4 (2k+1 is odd,
// never crosses a multiple of 16), so both groups use the same X,Y points;
// only the 5-seed masks differ. QUEST/tail run SIMT-shared for both groups.
// Exactness:
//  * final procrustes re-fits weights already fit in the loop -> saved
//    R,t,sq at (it==0 || improved) reproduce it bit-identically (per group).
//  * per-group early-exit: frozen group recomputes identical fit -> improved
//    stays false; loop exits when no group improved (= reference fixed point).
//  * residual classify: f32 with f64 recheck inside |sq32-TH2|<1e-4 band
//    (f32 error there ~5e-6, 20x margin) -> decisions f64-exact. ----
__global__ __launch_bounds__(64) void pose_fit_kernel(
    const float* __restrict__ kps0, const float* __restrict__ kps1,
    const float* __restrict__ depth0, const float* __restrict__ depth1,
    const float* __restrict__ T01,
    const float* __restrict__ K0, const float* __restrict__ K1,
    const int* __restrict__ sidx, const int* __restrict__ sransac,
    double* __restrict__ oscore, double* __restrict__ olr,
    double* __restrict__ olt) {
  const int blk  = blockIdx.x;     // 0..1023
  const int lane = threadIdx.x;    // 0..63
  const int grp  = lane >> 5;      // 0,1
  const int gl   = lane & 31;      // lane in group
  const int m = blk * 2 + grp;     // candidate (0..2047)
  const int v = m >> 4;            // sample row (same for both groups)
  const int b = v >> 4;            // batch

  double Ki0[3][3], Ki1[3][3];
  inv3(K0 + b * 9, Ki0);
  inv3(K1 + b * 9, Ki1);

  // gather + backproject 8 points per lane (f64); both groups same data
  double X[8][3], Y[8][3];
#pragma unroll
  for (int k = 0; k < 8; ++k) {
    int s = gl + 32 * k;
    int idx = sidx[v * S + s];
    int i0 = idx >> 10;       // idx / NK
    int i1 = idx & (NK - 1);  // idx % NK
    double u0 = (double)kps0[b * 2 * NK + i0];
    double w0 = (double)kps0[b * 2 * NK + NK + i0];
    double d0 = (double)depth0[b * NK + i0];
    double u1 = (double)kps1[b * 2 * NK + i1];
    double w1 = (double)kps1[b * 2 * NK + NK + i1];
    double d1 = (double)depth1[b * NK + i1];
#pragma unroll
    for (int i = 0; i < 3; ++i) {
      X[k][i] = d0 * (Ki0[i][0] * u0 + Ki0[i][1] * w0 + Ki0[i][2]);
      Y[k][i] = d1 * (Ki1[i][0] * u1 + Ki1[i][1] * w1 + Ki1[i][2]);
    }
  }

  // seed mask (bit k <=> point s = gl + 32k); set-semantics via OR
  unsigned wm = 0;
#pragma unroll
  for (int c = 0; c < 5; ++c) {
    int r = sransac[m * 5 + c];
    if ((r & 31) == gl) wm |= 1u << (r >> 5);
  }

  int pre = 5;  // NC (refsum/pre are exact small ints)
  float Rs[9], ts[3], sqs[8];  // saved state for inl_final fit (f32 tail)
  for (int it = 0; it < NREF; ++it) {
    double R[3][3], t[3];
    fitq(X, Y, wm, R, t);
    float r32[9] = {(float)R[0][0], (float)R[0][1], (float)R[0][2],
                    (float)R[1][0], (float)R[1][1], (float)R[1][2],
                    (float)R[2][0], (float)R[2][1], (float)R[2][2]};
    float t0 = (float)t[0], t1 = (float)t[1], t2 = (float)t[2];
    unsigned nwm = 0, band = 0;
    float sq32[8];
#pragma unroll
    for (int k = 0; k < 8; ++k) {
      float x0 = (float)X[k][0], x1 = (float)X[k][1], x2 = (float)X[k][2];
      float e0 = (float)Y[k][0] - (r32[0] * x0 + r32[1] * x1 + r32[2] * x2 + t0);
      float e1 = (float)Y[k][1] - (r32[3] * x0 + r32[4] * x1 + r32[5] * x2 + t1);
      float e2 = (float)Y[k][2] - (r32[6] * x0 + r32[7] * x1 + r32[8] * x2 + t2);
      float sq = e0 * e0 + e1 * e1 + e2 * e2;
      sq32[k] = sq;
      nwm  |= (sq < 0.0225f) ? (1u << k) : 0u;
      band |= (fabsf(sq - 0.0225f) < 1e-4f) ? (1u << k) : 0u;
    }
    if (__any(band != 0)) {  // rare: f64 recheck in the uncertainty band
#pragma unroll
      for (int k = 0; k < 8; ++k)
        if ((band >> k) & 1u) {
          double e0 = Y[k][0] - (R[0][0] * X[k][0] + R[0][1] * X[k][1] + R[0][2] * X[k][2] + t[0]);
          double e1 = Y[k][1] - (R[1][0] * X[k][0] + R[1][1] * X[k][1] + R[1][2] * X[k][2] + t[1]);
          double e2 = Y[k][2] - (R[2][0] * X[k][0] + R[2][1] * X[k][1] + R[2][2] * X[k][2] + t[2]);
          double sqd = e0 * e0 + e1 * e1 + e2 * e2;
          nwm = (nwm & ~(1u << k)) | ((sqd < 0.0225) ? (1u << k) : 0u);
        }
    }
    int rs = gsum(__popc(nwm));        // group-uniform refsum
    bool imp = rs > pre;
    bool sv = (it == 0) || imp;        // this fit is (currently) the final one
#pragma unroll
    for (int i = 0; i < 9; ++i) Rs[i] = sv ? r32[i] : Rs[i];
    ts[0] = sv ? t0 : ts[0]; ts[1] = sv ? t1 : ts[1]; ts[2] = sv ? t2 : ts[2];
#pragma unroll
    for (int k = 0; k < 8; ++k) sqs[k] = sv ? sq32[k] : sqs[k];
    pre = imp ? rs : pre;
    wm  = imp ? nwm : wm;
    if (!__any(imp)) break;  // per-group fixed point; wave exits together
  }

  // smooth score from saved residuals (f32 tail: no thresholds downstream)
  float sc = 0.0f;
#pragma unroll
  for (int k = 0; k < 8; ++k) {
    float r = sqrtf(sqs[k]);
    float xar = 5.0f * (1.0f - r * (1.0f / 0.15f));  // BETA*(1-r/TH)
    sc += 1.0f / (1.0f + __expf(-xar));
  }
  sc = gsum(sc);

  // pose errors vs ground truth T_0to1[b] (smooth path, f32)
  const float* Tb = T01 + b * 16;
  float tr = 0.0f;
#pragma unroll
  for (int i = 0; i < 3; ++i)
#pragma unroll
    for (int j = 0; j < 3; ++j) tr += Rs[i * 3 + j] * Tb[i * 4 + j];
  double xcl = 0.5 * ((double)tr - 1.0);
  const double lo = -1.0 + 1e-6, hi = 1.0 - 1e-6;
  xcl = xcl < lo ? lo : (xcl > hi ? hi : xcl);
  float rot_err = acosf((float)xcl) * (float)(180.0 / M_PI);
  float te0 = ts[0] - Tb[3];
  float te1 = ts[1] - Tb[7];
  float te2 = ts[2] - Tb[11];
  float terr = sqrtf(te0 * te0 + te1 * te1 + te2 * te2);
  float lr = 45.0f * tanhf(rot_err * (1.0f / 45.0f));  // MAX_ROT
  float lt = tanhf(terr);                              // MAX_TRANS = 1

  if (gl == 0) {  // lane 0 and lane 32 write their group's candidate
    oscore[m] = (double)sc;
    olr[m] = (double)lr;
    olt[m] = (double)lt;
  }
}

// ---- softmax(score/TEMP) over IT_R=16, weighted losses, mean over IT_M=16 ----
// Output is FLOAT32, flat (2, B, 1) = [rot x8, trans x8].
__global__ __launch_bounds__(128) void pose_reduce_kernel(
    const double* __restrict__ oscore, const double* __restrict__ olr,
    const double* __restrict__ olt, float* __restrict__ out) {
  __shared__ double slr[BV], slt[BV];
  int k = threadIdx.x;  // bv index 0..127
  double sc[16];
  double mx = -1e300;
#pragma unroll
  for (int r = 0; r < 16; ++r) {
    sc[r] = oscore[k * 16 + r];
    mx = fmax(mx, sc[r]);
  }
  double den = 0.0, wl = 0.0, wt = 0.0;
#pragma unroll
  for (int r = 0; r < 16; ++r) {
    double e = (double)__expf((float)((sc[r] - mx) * 0.1));  // /TEMP
    den += e;
    wl += e * olr[k * 16 + r];
    wt += e * olt[k * 16 + r];
  }
  slr[k] = wl / den;
  slt[k] = wt / den;
  __syncthreads();
  if (k < 8) {
    double a = 0.0, c = 0.0;
#pragma unroll
    for (int i = 0; i < 16; ++i) {
      a += slr[k * 16 + i];
      c += slt[k * 16 + i];
    }
    out[k]     = (float)(a / 16.0);  // losses_rot,   (2,B,1) flat
    out[8 + k] = (float)(c / 16.0);  // losses_trans
  }
}

}  // namespace mp

extern "C" void kernel_launch(void* const* d_in, const int* in_sizes, int n_in,
                              void* d_out, int out_size, void* d_ws, size_t ws_size,
                              hipStream_t stream) {
  // input order per setup_inputs(): 0 matches (unused), 1 kps0, 2 kps1,
  // 3 depth0, 4 depth1, 5 T_0to1, 6 K_color0, 7 K_color1, 8/9 Kori (unused),
  // 10 sampled_idx, 11 sampled_idx_ransac
  const float* kps0   = (const float*)d_in[1];
  const float* kps1   = (const float*)d_in[2];
  const float* depth0 = (const float*)d_in[3];
  const float* depth1 = (const float*)d_in[4];
  const float* T01    = (const float*)d_in[5];
  const float* K0     = (const float*)d_in[6];
  const float* K1     = (const float*)d_in[7];
  const int* sidx     = (const int*)d_in[10];
  const int* srans    = (const int*)d_in[11];

  double* ws     = (double*)d_ws;  // 3 * 2048 * 8B = 48 KB scratch
  double* oscore = ws;
  double* olr    = ws + mp::BIV;
  double* olt    = ws + 2 * mp::BIV;

  mp::pose_fit_kernel<<<mp::BIV / 2, 64, 0, stream>>>(
      kps0, kps1, depth0, depth1, T01, K0, K1, sidx, srans, oscore, olr, olt);
  mp::pose_reduce_kernel<<<1, 128, 0, stream>>>(
      oscore, olr, olt, (float*)d_out);
}